// Round 6
// baseline (398.823 us; speedup 1.0000x reference)
//
#include <hip/hip_runtime.h>

// SparseVoxelEncoder: trilinear interpolation of 8 corner embeddings per point.
// out[p, :] = sum_{c=0}^{7} w_c(p) * values[point_feats[sampled_idx[p]][c], :]
//
// R9: XCD-partitioned atomics experiment.
// Evidence so far: aux cost ~85-90 us is invariant to scatter-region size
// (67 MB / 67 MB+nt / 19 MB L2-fit all equal) -> write-allocate refuted; the
// 1M device-scope atomicAdds (~12 G/s) are the aux floor candidate. Device
// atomics can't retire in a requester's L2 unless the line is XCD-private
// (per-XCD L2s are not cross-coherent). Test: partition counts by
// x = blockIdx.x & 7 (workgroups dispatch round-robin over 8 XCDs), so each
// counts line is only ever touched by one XCD.
//   counts[8][H]   16.8 MB   atomic target, partition-private lines
//   bucket[H][24]  50.3 MB   id slots; slot = x*3 + pos  (CAP_X=3)
// Poisson(2/8)=0.25 per (voxel,partition): P(pos>=3) ~ 1e-5 -> ~50 overflow
// points total, computed directly in the scatter pass (identical FLOP order ->
// output stays bit-exact, absmax 0).
// Main kernel: lane sub owns partition sub (count + 3 slots, 12 B coalesced);
// iterates partitions via __shfl broadcast. Per-point math unchanged.
// If null -> device atomics are flat-rate at the fabric; atomic floor is
// structural and R7 stands as the practical optimum.

#define VOXEL_INV 4.0f  // 1 / 0.25
#define NPART 8
#define CAP_X 3         // slots per (voxel, partition)
#define SLOTS 24        // NPART * CAP_X per voxel

typedef float vfloat4 __attribute__((ext_vector_type(4)));

// ---- shared per-point math (identical FLOP order everywhere -> bit-identical)
__device__ __forceinline__ void corner_ids(const int* __restrict__ point_feats,
                                           int vi, int* ids)
{
    const int4* pf4 = (const int4*)(point_feats + ((size_t)vi << 3));
    int4 f0 = pf4[0];
    int4 f1 = pf4[1];
    ids[0] = f0.x; ids[1] = f0.y; ids[2] = f0.z; ids[3] = f0.w;
    ids[4] = f1.x; ids[5] = f1.y; ids[6] = f1.z; ids[7] = f1.w;
}

// full 32-float row for one point, single thread (rare overflow path)
__device__ void compute_point_direct(
    const float* __restrict__ point_xyz,
    const float* __restrict__ values,
    const int*   __restrict__ point_feats,
    float*       __restrict__ out,
    int vi, int p, float sx, float sy, float sz)
{
    float cx = point_xyz[(size_t)vi * 3 + 0];
    float cy = point_xyz[(size_t)vi * 3 + 1];
    float cz = point_xyz[(size_t)vi * 3 + 2];

    float px = (sx - cx) * VOXEL_INV + 0.5f;
    float py = (sy - cy) * VOXEL_INV + 0.5f;
    float pz = (sz - cz) * VOXEL_INV + 0.5f;

    float xs[2] = {1.0f - px, px};
    float ys[2] = {1.0f - py, py};
    float zs[2] = {1.0f - pz, pz};

    int ids[8];
    corner_ids(point_feats, vi, ids);

    vfloat4 acc[8] = {};
#pragma unroll
    for (int c = 0; c < 8; ++c) {
        float w = xs[(c >> 2) & 1] * ys[(c >> 1) & 1] * zs[c & 1];
        const vfloat4* vr = (const vfloat4*)(values + ((size_t)ids[c] << 5));
#pragma unroll
        for (int k = 0; k < 8; ++k) acc[k] += w * vr[k];
    }
    vfloat4* o = (vfloat4*)(out + ((size_t)p << 5));
#pragma unroll
    for (int k = 0; k < 8; ++k) __builtin_nontemporal_store(acc[k], o + k);
}

// ---------------------------------------------------------------- direct path
__global__ __launch_bounds__(256) void svenc_direct(
    const float* __restrict__ sampled_xyz,
    const float* __restrict__ point_xyz,
    const float* __restrict__ values,
    const int*   __restrict__ sampled_idx,
    const int*   __restrict__ point_feats,
    float*       __restrict__ out,
    int P)
{
    int t   = blockIdx.x * blockDim.x + threadIdx.x;
    int pid = t >> 3;
    int sub = t & 7;
    if (pid >= P) return;

    int vi = __builtin_nontemporal_load(sampled_idx + pid);
    float sx = __builtin_nontemporal_load(sampled_xyz + pid * 3 + 0);
    float sy = __builtin_nontemporal_load(sampled_xyz + pid * 3 + 1);
    float sz = __builtin_nontemporal_load(sampled_xyz + pid * 3 + 2);

    float cx = point_xyz[(size_t)vi * 3 + 0];
    float cy = point_xyz[(size_t)vi * 3 + 1];
    float cz = point_xyz[(size_t)vi * 3 + 2];

    float px = (sx - cx) * VOXEL_INV + 0.5f;
    float py = (sy - cy) * VOXEL_INV + 0.5f;
    float pz = (sz - cz) * VOXEL_INV + 0.5f;

    float xs[2] = {1.0f - px, px};
    float ys[2] = {1.0f - py, py};
    float zs[2] = {1.0f - pz, pz};

    int ids[8];
    corner_ids(point_feats, vi, ids);

    vfloat4 acc = {0.0f, 0.0f, 0.0f, 0.0f};
#pragma unroll
    for (int c = 0; c < 8; ++c) {
        float w = xs[(c >> 2) & 1] * ys[(c >> 1) & 1] * zs[c & 1];
        const vfloat4 v = ((const vfloat4*)(values + ((size_t)ids[c] << 5)))[sub];
        acc += w * v;
    }
    __builtin_nontemporal_store(acc, (vfloat4*)(out + ((size_t)pid << 5)) + sub);
}

// --------------------------------------------- partitioned id-bucket scatter
__global__ __launch_bounds__(256) void k_bucket_part(
    const float* __restrict__ sampled_xyz,
    const float* __restrict__ point_xyz,
    const float* __restrict__ values,
    const int*   __restrict__ sampled_idx,
    const int*   __restrict__ point_feats,
    float*       __restrict__ out,
    int*         __restrict__ counts,    // [NPART][H] — partition-private lines
    int*         __restrict__ bucket,    // [H][SLOTS]
    int P, int H)
{
    int p = blockIdx.x * 256 + threadIdx.x;
    if (p >= P) return;

    int x  = blockIdx.x & (NPART - 1);   // partition == (assumed) XCD id
    int vi = __builtin_nontemporal_load(sampled_idx + p);

    int pos = atomicAdd(counts + (size_t)x * H + vi, 1);
    if (pos < CAP_X) {
        bucket[(size_t)vi * SLOTS + x * CAP_X + pos] = p;
    } else {
        // rare (~50 points total): compute in-place, fully correct
        float sx = sampled_xyz[(size_t)p * 3 + 0];
        float sy = sampled_xyz[(size_t)p * 3 + 1];
        float sz = sampled_xyz[(size_t)p * 3 + 2];
        compute_point_direct(point_xyz, values, point_feats, out, vi, p, sx, sy, sz);
    }
}

// ---------------------------------------------------------------- main kernel
__global__ __launch_bounds__(256) void svenc_voxel_part(
    const float* __restrict__ sampled_xyz,
    const float* __restrict__ point_xyz,
    const float* __restrict__ values,
    const int*   __restrict__ point_feats,
    const int*   __restrict__ counts,    // [NPART][H]
    const int*   __restrict__ bucket,    // [H][SLOTS]
    float*       __restrict__ out,
    int H)
{
    int t    = blockIdx.x * 256 + threadIdx.x;
    int g    = t >> 3;       // voxel index
    int sub  = t & 7;        // partition index AND float4 chunk of the row
    int lane = threadIdx.x & 63;
    int grpbase = lane & 56; // first lane of this voxel's 8-lane group
    if (g >= H) return;

    // lane sub owns partition sub: its count (capped) and its 3 slots (12 B)
    int c = counts[(size_t)sub * H + g];
    if (c > CAP_X) c = CAP_X;
    const int* bs = bucket + (size_t)g * SLOTS + sub * CAP_X;
    int s0 = bs[0], s1 = bs[1], s2 = bs[2];

    // skip empty voxels (13.5% at lambda=2)
    unsigned long long any = __ballot(c > 0);
    if (((any >> grpbase) & 0xFFull) == 0) return;

    float cx = point_xyz[(size_t)g * 3 + 0];
    float cy = point_xyz[(size_t)g * 3 + 1];
    float cz = point_xyz[(size_t)g * 3 + 2];

    int ids[8];
    corner_ids(point_feats, g, ids);

    // 8 corner rows loaded ONCE into registers, reused for all points in voxel
    vfloat4 v[8];
#pragma unroll
    for (int cc = 0; cc < 8; ++cc)
        v[cc] = ((const vfloat4*)(values + ((size_t)ids[cc] << 5)))[sub];

    auto body = [&](int p) {
        // broadcast gather: 8 lanes read the same 12 B (merged by HW)
        float sx = sampled_xyz[(size_t)p * 3 + 0];
        float sy = sampled_xyz[(size_t)p * 3 + 1];
        float sz = sampled_xyz[(size_t)p * 3 + 2];

        float px = (sx - cx) * VOXEL_INV + 0.5f;
        float py = (sy - cy) * VOXEL_INV + 0.5f;
        float pz = (sz - cz) * VOXEL_INV + 0.5f;

        float xs[2] = {1.0f - px, px};
        float ys[2] = {1.0f - py, py};
        float zs[2] = {1.0f - pz, pz};

        vfloat4 acc = {0.0f, 0.0f, 0.0f, 0.0f};
#pragma unroll
        for (int cc = 0; cc < 8; ++cc) {
            float w = xs[(cc >> 2) & 1] * ys[(cc >> 1) & 1] * zs[cc & 1];
            acc += w * v[cc];
        }
        __builtin_nontemporal_store(acc, (vfloat4*)(out + ((size_t)p << 5)) + sub);
    };

    for (int x = 0; x < NPART; ++x) {
        int nx = __shfl(c, grpbase + x, 64);
        if (nx == 0) continue;
        int p0 = __shfl(s0, grpbase + x, 64);
        body(p0);
        if (nx > 1) { int p1 = __shfl(s1, grpbase + x, 64); body(p1); }
        if (nx > 2) { int p2 = __shfl(s2, grpbase + x, 64); body(p2); }
    }
}

// ---------------------------------------------------------------- launcher
extern "C" void kernel_launch(void* const* d_in, const int* in_sizes, int n_in,
                              void* d_out, int out_size, void* d_ws, size_t ws_size,
                              hipStream_t stream) {
    const float* sampled_xyz = (const float*)d_in[0];
    const float* point_xyz   = (const float*)d_in[1];
    const float* values      = (const float*)d_in[2];
    const int*   sampled_idx = (const int*)d_in[3];
    const int*   point_feats = (const int*)d_in[4];
    float* out = (float*)d_out;

    int P = in_sizes[3];   // element count of sampled_idx == number of points

    // H: handle both in_sizes conventions (total elements vs first-dim).
    int H;
    if (in_sizes[0] == 3 * P)       H = in_sizes[4] / 8;
    else                            H = in_sizes[4];

    size_t bucketB = (size_t)H * SLOTS * 4;          // 50.3 MB
    size_t countsB = (size_t)NPART * H * 4;          // 16.8 MB
    size_t need    = bucketB + countsB;              // 67.1 MB (<= 69.2 proven)

    if (d_ws != nullptr && ws_size >= need && H > 0) {
        int* bucket = (int*)d_ws;
        int* counts = (int*)((char*)d_ws + bucketB);
        hipMemsetAsync(counts, 0, countsB, stream);

        int gp = (P + 255) / 256;
        k_bucket_part<<<gp, 256, 0, stream>>>(
            sampled_xyz, point_xyz, values, sampled_idx, point_feats,
            out, counts, bucket, P, H);

        long tt = (long)H * 8;
        int gm = (int)((tt + 255) / 256);
        svenc_voxel_part<<<gm, 256, 0, stream>>>(
            sampled_xyz, point_xyz, values, point_feats, counts, bucket, out, H);
    } else {
        long total_threads = (long)P * 8;
        int grid = (int)((total_threads + 255) / 256);
        svenc_direct<<<grid, 256, 0, stream>>>(
            sampled_xyz, point_xyz, values, sampled_idx, point_feats, out, P);
    }
}

// Round 7
// 362.163 us; speedup vs baseline: 1.1012x; 1.1012x over previous
//
#include <hip/hip_runtime.h>

// SparseVoxelEncoder: trilinear interpolation of 8 corner embeddings per point.
// out[p, :] = sum_{c=0}^{7} w_c(p) * values[point_feats[sampled_idx[p]][c], :]
//
// R10 = revert to R7 (best measured: 362.5 us bench, 121.8 us main, absmax 0).
// R8 (19 MB L2-resident bucket) and R9 (XCD-partitioned atomics) were both
// null/regressions, completing the characterization of the aux floor:
//   any pass touching 1M random 4-16 B locations costs ~80-90 us, invariant to
//   region size (67 vs 19 MB), cache-policy hints (nt / nt sc0 sc1 — 4/4 null
//   on this chip), payload width, and XCD line-partitioning. Atomic+scatter
//   rate is fabric-flat.
// Ledger / floor model (measured):
//   156 us  fixed harness overhead (R1: 377.1 bench - 221.0 kernel)
//   122 us  main = random-128B-line pattern floor (~3.5 TB/s scattered-line BW;
//           dur invariant at 122-127 us while FETCH varied 258->304 MB)
//    85 us  bucket pass = scatter/atomic floor (five structural variants)
//   = ~363 us == R7's measured 362.5. Direct (no-aux) family floors at 377.
//
// Structure: fused bucket-scatter (atomicAdd slot assignment, xyz carried in
// the 16-B bucket entry) + voxel-grouped main (8 lanes/voxel, 8 corner rows
// loaded once into registers, reused for all ~2 points of the voxel).
// Overflow (count>CAP, ~1e2 points, Poisson(2)): computed in-pass with
// identical FLOP order -> output bit-exact (absmax 0).

#define VOXEL_INV 4.0f  // 1 / 0.25
#define CAP 8           // bucket slots per voxel (128 B = one line per voxel)

typedef float vfloat4 __attribute__((ext_vector_type(4)));

// ---- shared per-point math (identical FLOP order everywhere -> bit-identical)
__device__ __forceinline__ void corner_ids(const int* __restrict__ point_feats,
                                           int vi, int* ids)
{
    const int4* pf4 = (const int4*)(point_feats + ((size_t)vi << 3));
    int4 f0 = pf4[0];
    int4 f1 = pf4[1];
    ids[0] = f0.x; ids[1] = f0.y; ids[2] = f0.z; ids[3] = f0.w;
    ids[4] = f1.x; ids[5] = f1.y; ids[6] = f1.z; ids[7] = f1.w;
}

// full 32-float row for one point, single thread (rare overflow path)
__device__ void compute_point_direct(
    const float* __restrict__ point_xyz,
    const float* __restrict__ values,
    const int*   __restrict__ point_feats,
    float*       __restrict__ out,
    int vi, int p, float sx, float sy, float sz)
{
    float cx = point_xyz[(size_t)vi * 3 + 0];
    float cy = point_xyz[(size_t)vi * 3 + 1];
    float cz = point_xyz[(size_t)vi * 3 + 2];

    float px = (sx - cx) * VOXEL_INV + 0.5f;
    float py = (sy - cy) * VOXEL_INV + 0.5f;
    float pz = (sz - cz) * VOXEL_INV + 0.5f;

    float xs[2] = {1.0f - px, px};
    float ys[2] = {1.0f - py, py};
    float zs[2] = {1.0f - pz, pz};

    int ids[8];
    corner_ids(point_feats, vi, ids);

    vfloat4 acc[8] = {};
#pragma unroll
    for (int c = 0; c < 8; ++c) {
        float w = xs[(c >> 2) & 1] * ys[(c >> 1) & 1] * zs[c & 1];
        const vfloat4* vr = (const vfloat4*)(values + ((size_t)ids[c] << 5));
#pragma unroll
        for (int k = 0; k < 8; ++k) acc[k] += w * vr[k];
    }
    vfloat4* o = (vfloat4*)(out + ((size_t)p << 5));
#pragma unroll
    for (int k = 0; k < 8; ++k) __builtin_nontemporal_store(acc[k], o + k);
}

// ---------------------------------------------------------------- direct path
__global__ __launch_bounds__(256) void svenc_direct(
    const float* __restrict__ sampled_xyz,
    const float* __restrict__ point_xyz,
    const float* __restrict__ values,
    const int*   __restrict__ sampled_idx,
    const int*   __restrict__ point_feats,
    float*       __restrict__ out,
    int P)
{
    int t   = blockIdx.x * blockDim.x + threadIdx.x;
    int pid = t >> 3;
    int sub = t & 7;
    if (pid >= P) return;

    int vi = __builtin_nontemporal_load(sampled_idx + pid);
    float sx = __builtin_nontemporal_load(sampled_xyz + pid * 3 + 0);
    float sy = __builtin_nontemporal_load(sampled_xyz + pid * 3 + 1);
    float sz = __builtin_nontemporal_load(sampled_xyz + pid * 3 + 2);

    float cx = point_xyz[(size_t)vi * 3 + 0];
    float cy = point_xyz[(size_t)vi * 3 + 1];
    float cz = point_xyz[(size_t)vi * 3 + 2];

    float px = (sx - cx) * VOXEL_INV + 0.5f;
    float py = (sy - cy) * VOXEL_INV + 0.5f;
    float pz = (sz - cz) * VOXEL_INV + 0.5f;

    float xs[2] = {1.0f - px, px};
    float ys[2] = {1.0f - py, py};
    float zs[2] = {1.0f - pz, pz};

    int ids[8];
    corner_ids(point_feats, vi, ids);

    vfloat4 acc = {0.0f, 0.0f, 0.0f, 0.0f};
#pragma unroll
    for (int c = 0; c < 8; ++c) {
        float w = xs[(c >> 2) & 1] * ys[(c >> 1) & 1] * zs[c & 1];
        const vfloat4 v = ((const vfloat4*)(values + ((size_t)ids[c] << 5)))[sub];
        acc += w * v;
    }
    __builtin_nontemporal_store(acc, (vfloat4*)(out + ((size_t)pid << 5)) + sub);
}

// ------------------------------------------------------- tier 1: xyz buckets
__global__ __launch_bounds__(256) void k_bucket_xyz(
    const float* __restrict__ sampled_xyz,
    const float* __restrict__ point_xyz,
    const float* __restrict__ values,
    const int*   __restrict__ sampled_idx,
    const int*   __restrict__ point_feats,
    float*       __restrict__ out,
    int*         __restrict__ counts,
    vfloat4*     __restrict__ bucket,   // [H*CAP] {bitcast(p), sx, sy, sz}
    int P)
{
    int p = blockIdx.x * 256 + threadIdx.x;
    if (p >= P) return;

    int vi = __builtin_nontemporal_load(sampled_idx + p);

    // issue the atomic FIRST (independent of xyz) so its latency overlaps
    // the xyz loads
    int pos = atomicAdd(counts + vi, 1);

    float sx = __builtin_nontemporal_load(sampled_xyz + (size_t)p * 3 + 0);
    float sy = __builtin_nontemporal_load(sampled_xyz + (size_t)p * 3 + 1);
    float sz = __builtin_nontemporal_load(sampled_xyz + (size_t)p * 3 + 2);

    if (pos < CAP) {
        vfloat4 e;
        e.x = __int_as_float(p);
        e.y = sx; e.z = sy; e.w = sz;
        __builtin_nontemporal_store(e, bucket + ((size_t)vi << 3) + pos);
    } else {
        // rare (~1e2 points total): compute in-place, fully correct
        compute_point_direct(point_xyz, values, point_feats, out, vi, p, sx, sy, sz);
    }
}

__global__ __launch_bounds__(256) void svenc_voxel_xyz(
    const float* __restrict__ point_xyz,
    const float* __restrict__ values,
    const int*   __restrict__ point_feats,
    const int*   __restrict__ counts,
    const vfloat4* __restrict__ bucket,
    float*       __restrict__ out,
    int H)
{
    int t   = blockIdx.x * 256 + threadIdx.x;
    int g   = t >> 3;       // voxel index (sequential -> streaming voxel tables)
    int sub = t & 7;        // float4 chunk of the 32-float row
    if (g >= H) return;

    int n = __builtin_nontemporal_load(counts + g);   // read-once stream
    if (n == 0) return;
    if (n > CAP) n = CAP;

    float cx = point_xyz[(size_t)g * 3 + 0];
    float cy = point_xyz[(size_t)g * 3 + 1];
    float cz = point_xyz[(size_t)g * 3 + 2];

    int ids[8];
    corner_ids(point_feats, g, ids);

    // 8 corner rows loaded ONCE into registers, reused for all points in voxel
    vfloat4 v[8];
#pragma unroll
    for (int c = 0; c < 8; ++c)
        v[c] = ((const vfloat4*)(values + ((size_t)ids[c] << 5)))[sub];

    for (int i = 0; i < n; ++i) {
        vfloat4 e = __builtin_nontemporal_load(bucket + ((size_t)g << 3) + i);
        int p = __float_as_int(e.x);

        float px = (e.y - cx) * VOXEL_INV + 0.5f;
        float py = (e.z - cy) * VOXEL_INV + 0.5f;
        float pz = (e.w - cz) * VOXEL_INV + 0.5f;

        float xs[2] = {1.0f - px, px};
        float ys[2] = {1.0f - py, py};
        float zs[2] = {1.0f - pz, pz};

        vfloat4 acc = {0.0f, 0.0f, 0.0f, 0.0f};
#pragma unroll
        for (int c = 0; c < 8; ++c) {
            float w = xs[(c >> 2) & 1] * ys[(c >> 1) & 1] * zs[c & 1];
            acc += w * v[c];
        }
        __builtin_nontemporal_store(acc, (vfloat4*)(out + ((size_t)p << 5)) + sub);
    }
}

// -------------------------------------------------------- tier 2: id buckets
__global__ __launch_bounds__(256) void k_bucket_id(
    const float* __restrict__ sampled_xyz,
    const float* __restrict__ point_xyz,
    const float* __restrict__ values,
    const int*   __restrict__ sampled_idx,
    const int*   __restrict__ point_feats,
    float*       __restrict__ out,
    int*         __restrict__ counts,
    int*         __restrict__ bucket,   // [H*CAP] point ids
    int P)
{
    int p = blockIdx.x * 256 + threadIdx.x;
    if (p >= P) return;

    int vi = sampled_idx[p];
    int pos = atomicAdd(counts + vi, 1);
    if (pos < CAP) {
        __builtin_nontemporal_store(p, bucket + ((size_t)vi << 3) + pos);
    } else {
        float sx = sampled_xyz[(size_t)p * 3 + 0];
        float sy = sampled_xyz[(size_t)p * 3 + 1];
        float sz = sampled_xyz[(size_t)p * 3 + 2];
        compute_point_direct(point_xyz, values, point_feats, out, vi, p, sx, sy, sz);
    }
}

__global__ __launch_bounds__(256) void svenc_voxel_id(
    const float* __restrict__ sampled_xyz,
    const float* __restrict__ point_xyz,
    const float* __restrict__ values,
    const int*   __restrict__ point_feats,
    const int*   __restrict__ counts,
    const int*   __restrict__ bucket,
    float*       __restrict__ out,
    int H)
{
    int t   = blockIdx.x * 256 + threadIdx.x;
    int g   = t >> 3;
    int sub = t & 7;
    if (g >= H) return;

    int n = counts[g];
    if (n == 0) return;
    if (n > CAP) n = CAP;

    float cx = point_xyz[(size_t)g * 3 + 0];
    float cy = point_xyz[(size_t)g * 3 + 1];
    float cz = point_xyz[(size_t)g * 3 + 2];

    int ids[8];
    corner_ids(point_feats, g, ids);

    vfloat4 v[8];
#pragma unroll
    for (int c = 0; c < 8; ++c)
        v[c] = ((const vfloat4*)(values + ((size_t)ids[c] << 5)))[sub];

    for (int i = 0; i < n; ++i) {
        int p = bucket[((size_t)g << 3) + i];

        float sx = sampled_xyz[(size_t)p * 3 + 0];
        float sy = sampled_xyz[(size_t)p * 3 + 1];
        float sz = sampled_xyz[(size_t)p * 3 + 2];

        float px = (sx - cx) * VOXEL_INV + 0.5f;
        float py = (sy - cy) * VOXEL_INV + 0.5f;
        float pz = (sz - cz) * VOXEL_INV + 0.5f;

        float xs[2] = {1.0f - px, px};
        float ys[2] = {1.0f - py, py};
        float zs[2] = {1.0f - pz, pz};

        vfloat4 acc = {0.0f, 0.0f, 0.0f, 0.0f};
#pragma unroll
        for (int c = 0; c < 8; ++c) {
            float w = xs[(c >> 2) & 1] * ys[(c >> 1) & 1] * zs[c & 1];
            acc += w * v[c];
        }
        __builtin_nontemporal_store(acc, (vfloat4*)(out + ((size_t)p << 5)) + sub);
    }
}

// ---------------------------------------------------------------- launcher
extern "C" void kernel_launch(void* const* d_in, const int* in_sizes, int n_in,
                              void* d_out, int out_size, void* d_ws, size_t ws_size,
                              hipStream_t stream) {
    const float* sampled_xyz = (const float*)d_in[0];
    const float* point_xyz   = (const float*)d_in[1];
    const float* values      = (const float*)d_in[2];
    const int*   sampled_idx = (const int*)d_in[3];
    const int*   point_feats = (const int*)d_in[4];
    float* out = (float*)d_out;

    int P = in_sizes[3];   // element count of sampled_idx == number of points

    // H: handle both in_sizes conventions (total elements vs first-dim).
    int H;
    if (in_sizes[0] == 3 * P)       H = in_sizes[4] / 8;
    else                            H = in_sizes[4];

    size_t bucketB_xyz = (size_t)H * CAP * 16;   // vfloat4 per slot
    size_t need_xyz    = bucketB_xyz + (size_t)H * 4;
    size_t bucketB_id  = (size_t)H * CAP * 4;
    size_t need_id     = bucketB_id + (size_t)H * 4;

    int gp = (P + 255) / 256;                    // one thread per point
    long tt = (long)H * 8;
    int gm = (int)((tt + 255) / 256);            // 8 lanes per voxel

    if (d_ws != nullptr && ws_size >= need_xyz && H > 0) {
        vfloat4* bucket = (vfloat4*)d_ws;
        int* counts = (int*)((char*)d_ws + bucketB_xyz);
        hipMemsetAsync(counts, 0, (size_t)H * 4, stream);
        k_bucket_xyz<<<gp, 256, 0, stream>>>(
            sampled_xyz, point_xyz, values, sampled_idx, point_feats,
            out, counts, bucket, P);
        svenc_voxel_xyz<<<gm, 256, 0, stream>>>(
            point_xyz, values, point_feats, counts, bucket, out, H);
    } else if (d_ws != nullptr && ws_size >= need_id && H > 0) {
        int* bucket = (int*)d_ws;
        int* counts = (int*)((char*)d_ws + bucketB_id);
        hipMemsetAsync(counts, 0, (size_t)H * 4, stream);
        k_bucket_id<<<gp, 256, 0, stream>>>(
            sampled_xyz, point_xyz, values, sampled_idx, point_feats,
            out, counts, bucket, P);
        svenc_voxel_id<<<gm, 256, 0, stream>>>(
            sampled_xyz, point_xyz, values, point_feats, counts, bucket, out, H);
    } else {
        long total_threads = (long)P * 8;
        int grid = (int)((total_threads + 255) / 256);
        svenc_direct<<<grid, 256, 0, stream>>>(
            sampled_xyz, point_xyz, values, sampled_idx, point_feats, out, P);
    }
}